// Round 19
// baseline (428.310 us; speedup 1.0000x reference)
//
#include <hip/hip_runtime.h>
#include <stdint.h>
#include <math.h>

typedef unsigned long long u64;

#define CH     4096    // rows per chunk
#define FTH    256     // threads per block
#define SLOTC  2048    // key slots per chunk region
#define KOUT   512
#define DIRECT 1024    // L <= DIRECT: keep all rows (chunk 0 only)
#define NBK    1024    // merge counting-sort buckets
#define FNB    4096    // fallback bins (global)
#define FCAP   2048    // fallback candidates (global)
#define NCHMAX 16

__device__ __forceinline__ uint32_t fmap(float f) {
    uint32_t u = __float_as_uint(f);
    return (u & 0x80000000u) ? ~u : (u | 0x80000000u);
}
__device__ __forceinline__ float funmap(uint32_t m) {
    uint32_t u = (m & 0x80000000u) ? (m & 0x7fffffffu) : ~m;
    return __uint_as_float(u);
}
__device__ __forceinline__ u64 pack(float x, float y) {
    return ((u64)fmap(x) << 32) | (u64)fmap(y);
}

__device__ __forceinline__ float norm_icdf(float p) {
    const float a1=-3.969683028665376e+01f,a2= 2.209460984245205e+02f,a3=-2.759285104469687e+02f,
                a4= 1.383577518672690e+02f,a5=-3.066479806614716e+01f,a6= 2.506628277459239e+00f;
    const float b1=-5.447609879822406e+01f,b2= 1.615858368580409e+02f,b3=-1.556989798598866e+02f,
                b4= 6.680131188771972e+01f,b5=-1.328068155288572e+01f;
    const float c1=-7.784894002430293e-03f,c2=-3.223964580411365e-01f,c3=-2.400758277161838e+00f,
                c4=-2.549732539343734e+00f,c5= 4.374664141464968e+00f,c6= 2.938163982698783e+00f;
    const float d1= 7.784695709041462e-03f,d2= 3.224671290700398e-01f,d3= 2.445134137142996e+00f,
                d4= 3.754408661907416e+00f;
    if (p < 0.02425f) {
        float q = sqrtf(-2.0f * logf(p));
        return (((((c1*q+c2)*q+c3)*q+c4)*q+c5)*q+c6) / ((((d1*q+d2)*q+d3)*q+d4)*q+1.0f);
    } else if (p <= 0.97575f) {
        float q = p - 0.5f, r = q*q;
        return (((((a1*r+a2)*r+a3)*r+a4)*r+a5)*r+a6)*q / (((((b1*r+b2)*r+b3)*r+b4)*r+b5)*r+1.0f);
    } else {
        float q = sqrtf(-2.0f * logf(1.0f - p));
        return -(((((c1*q+c2)*q+c3)*q+c4)*q+c5)*q+c6) / ((((d1*q+d2)*q+d3)*q+d4)*q+1.0f);
    }
}

__device__ __forceinline__ uint32_t bucket_of(u64 key, int L) {
    float x = funmap((uint32_t)(key >> 32));
    float p = 0.5f * (1.0f + erff(x * 0.70710678f));
    float s = (L > DIRECT) ? ((float)L * ((float)NBK / 768.0f)) : (float)NBK;
    float fp = p * s;
    uint32_t bb = (uint32_t)fp;
    return (bb > (NBK - 1u)) ? (NBK - 1u) : bb;
}

__global__ __launch_bounds__(FTH) void topk_kernel(
    const float* __restrict__ corners, const int* __restrict__ lengths,
    float* __restrict__ out, u64* __restrict__ keys, uint32_t* __restrict__ counts,
    uint32_t* __restrict__ done, uint32_t* __restrict__ fbh, u64* __restrict__ fbc,
    int M, int NCH)
{
    const int blk = blockIdx.x;
    const int b = blk / NCH;
    const int qi = blk - b * NCH;
    const int tid = threadIdx.x;
    const int lane = tid & 63;

    int L = lengths[b];
    if (L < 0) L = 0;
    if (L > M) L = M;
    const int Kb = (L < KOUT) ? L : KOUT;

    __shared__ u64 sbuf[1024];
    __shared__ uint32_t bh[NBK], sc[NBK];
    __shared__ uint32_t wsum[4];
    __shared__ uint32_t craw[NCHMAX], cpre[NCHMAX + 1];
    __shared__ uint32_t shcnt, sdone, shT, gbad;

    const int start = qi * CH;
    int validq = L - start;
    if (validq < 0) validq = 0;
    if (validq > CH) validq = CH;

    u64* myk = keys + (size_t)blk * SLOTC;
    const float2* cpb = (const float2*)corners + (size_t)b * M;

    // ---- phase 1: filter own chunk into private global region ----
    if (validq > 0) {
        const float2* cp = cpb + start;
        if (L <= DIRECT) {                 // chunk 0 only: keep all
            for (int i = tid; i < validq; i += FTH)
                myk[i] = pack(cp[i].x, cp[i].y);
            if (tid == 0) counts[blk] = (uint32_t)validq;
        } else {
            if (tid == 0) shcnt = 0u;
            __syncthreads();
            const float tau = norm_icdf(768.0f / (float)L) + 0.01f;
            const float4* cp4 = (const float4*)cp;
            const int nv = validq >> 1;
            for (int i = tid; i < nv; i += FTH) {
                float4 v = cp4[i];
                bool k0 = (v.x <= tau), k1 = (v.z <= tau);
                u64 m0 = __ballot(k0), m1 = __ballot(k1);
                if (m0 | m1) {
                    int c0 = __popcll(m0);
                    uint32_t base = 0;
                    if (lane == 0) base = atomicAdd(&shcnt, (uint32_t)(c0 + __popcll(m1)));
                    base = __shfl(base, 0, 64);
                    u64 lt = ((u64)1 << lane) - 1ull;
                    if (k0) {
                        uint32_t s = base + (uint32_t)__popcll(m0 & lt);
                        if (s < SLOTC) myk[s] = pack(v.x, v.y);
                    }
                    if (k1) {
                        uint32_t s = base + (uint32_t)(c0 + __popcll(m1 & lt));
                        if (s < SLOTC) myk[s] = pack(v.z, v.w);
                    }
                }
            }
            if ((validq & 1) && tid == 0) {
                float2 c = cp[validq - 1];
                if (c.x <= tau) {
                    uint32_t s = atomicAdd(&shcnt, 1u);
                    if (s < SLOTC) myk[s] = pack(c.x, c.y);
                }
            }
            __syncthreads();
            if (tid == 0) counts[blk] = shcnt;   // raw; >SLOTC flags fallback
        }
    } else {
        if (tid == 0) counts[blk] = 0u;
    }

    // ---- completion handoff: last finisher merges ----
    __syncthreads();
    if (tid == 0) { __threadfence(); sdone = atomicAdd(&done[b], 1u); }
    __syncthreads();
    if (sdone != (uint32_t)(NCH - 1)) return;
    __threadfence();

    float2* outb = (float2*)(out + (size_t)b * (2 * KOUT));
    if (Kb == 0) {
        for (int j = tid; j < KOUT; j += FTH) outb[j] = make_float2(0.0f, 0.0f);
        return;
    }

    if (tid < NCH) craw[tid] = counts[b * NCH + tid];
    if (tid == 0) gbad = 0u;
    __syncthreads();
    if (tid == 0) {
        uint32_t run = 0;
        for (int q = 0; q < NCH; ++q) {
            cpre[q] = run;
            if (craw[q] > SLOTC) gbad = 1u;
            run += craw[q];
        }
        cpre[NCH] = run;
    }
    __syncthreads();
    const uint32_t n = cpre[NCH];

    if (!gbad && n >= (uint32_t)Kb && n <= 1024u) {
        // ---- normal merge: two-pass counting-sort from global keys ----
        for (int i = tid; i < NBK; i += FTH) bh[i] = 0u;
        __syncthreads();
        for (int q = 0; q < NCH; ++q) {
            const uint32_t c = craw[q];
            const u64* src = keys + (size_t)(b * NCH + q) * SLOTC;
            for (uint32_t i = tid; i < c; i += FTH)
                atomicAdd(&bh[bucket_of(src[i], L)], 1u);
        }
        __syncthreads();
        // scan 1024 bins, 4 per thread
        {
            const int t4 = tid * 4;
            uint32_t b0 = bh[t4], b1 = bh[t4+1], b2 = bh[t4+2], b3 = bh[t4+3];
            uint32_t s = b0 + b1 + b2 + b3;
            uint32_t v = s;
            const int wid = tid >> 6;
            for (int off = 1; off < 64; off <<= 1) {
                uint32_t t2 = __shfl_up(v, (unsigned)off, 64);
                if (lane >= off) v += t2;
            }
            if (lane == 63) wsum[wid] = v;
            __syncthreads();
            if (tid < 4) {
                uint32_t xv = wsum[tid];
                for (int off = 1; off < 4; off <<= 1) {
                    uint32_t t2 = __shfl_up(xv, (unsigned)off, 4);
                    if (tid >= off) xv += t2;
                }
                wsum[tid] = xv;
            }
            __syncthreads();
            const uint32_t woff = (wid > 0) ? wsum[wid - 1] : 0u;
            const uint32_t excl = v + woff - s;
            sc[t4] = excl; sc[t4+1] = excl + b0;
            sc[t4+2] = excl + b0 + b1; sc[t4+3] = excl + b0 + b1 + b2;
        }
        __syncthreads();
        for (int i = tid; i < NBK; i += FTH) bh[i] = 0u;
        __syncthreads();
        for (int q = 0; q < NCH; ++q) {
            const uint32_t c = craw[q];
            const u64* src = keys + (size_t)(b * NCH + q) * SLOTC;
            for (uint32_t i = tid; i < c; i += FTH) {
                u64 k = src[i];
                uint32_t bkt = bucket_of(k, L);
                uint32_t off = atomicAdd(&bh[bkt], 1u);
                sbuf[sc[bkt] + off] = k;
            }
        }
        __syncthreads();
        for (int j = Kb + tid; j < KOUT; j += FTH)
            outb[j] = make_float2(0.0f, 0.0f);
        for (uint32_t i = tid; i < n; i += FTH) {
            u64 key = sbuf[i];
            uint32_t bkt = bucket_of(key, L);
            const uint32_t s0 = sc[bkt];
            const uint32_t cnt = bh[bkt];
            uint32_t r = 0;
            for (uint32_t m = 0; m < cnt; ++m) {
                u64 kj = sbuf[s0 + m];
                r += (kj < key) || (kj == key && (s0 + m) < i);
            }
            uint32_t rank = s0 + r;
            if (rank < (uint32_t)Kb)
                outb[rank] = make_float2(funmap((uint32_t)(key >> 32)), funmap((uint32_t)key));
        }
        return;
    }

    // ---- exact fallback (statistically unreachable), global scratch ----
    uint32_t* gh = fbh + (size_t)b * FNB;
    u64* gc = fbc + (size_t)b * FCAP;
    if (tid == 0) { shcnt = 0u; shT = FNB - 1; }
    for (int i = tid; i < FNB; i += FTH) gh[i] = 0u;
    __syncthreads();
    for (int i = tid; i < L; i += FTH)
        atomicAdd(&gh[fmap(cpb[i].x) >> 20], 1u);
    __syncthreads();
    {   // parallel threshold scan: 16 bins per thread
        const int t16 = tid * 16;
        uint32_t s = 0;
        for (int g = 0; g < 16; ++g) s += gh[t16 + g];
        uint32_t v = s;
        const int wid = tid >> 6;
        for (int off = 1; off < 64; off <<= 1) {
            uint32_t t2 = __shfl_up(v, (unsigned)off, 64);
            if (lane >= off) v += t2;
        }
        if (lane == 63) wsum[wid] = v;
        __syncthreads();
        if (tid < 4) {
            uint32_t xv = wsum[tid];
            for (int off = 1; off < 4; off <<= 1) {
                uint32_t t2 = __shfl_up(xv, (unsigned)off, 4);
                if (tid >= off) xv += t2;
            }
            wsum[tid] = xv;
        }
        __syncthreads();
        const uint32_t woff = (wid > 0) ? wsum[wid - 1] : 0u;
        const uint32_t incl = v + woff;
        const uint32_t excl = incl - s;
        if ((uint32_t)Kb > excl && (uint32_t)Kb <= incl) {
            uint32_t run = excl;
            int g = 0;
            for (;;) {
                run += gh[t16 + g];
                if (run >= (uint32_t)Kb) break;
                ++g;
            }
            shT = (uint32_t)(t16 + g);
        }
        __syncthreads();
    }
    const uint32_t T = shT;
    for (int i = tid; i < L; i += FTH) {
        float2 c = cpb[i];
        uint32_t kx = fmap(c.x);
        if ((kx >> 20) <= T) {
            uint32_t p = atomicAdd(&shcnt, 1u);
            if (p < FCAP) gc[p] = ((u64)kx << 32) | fmap(c.y);
        }
    }
    __syncthreads();
    const int nn = (int)((shcnt < FCAP) ? shcnt : FCAP);
    for (int j = Kb + tid; j < KOUT; j += FTH)
        outb[j] = make_float2(0.0f, 0.0f);
    for (int i = tid; i < nn; i += FTH) {
        u64 ki = gc[i];
        uint32_t r = 0;
        for (int j = 0; j < nn; ++j) {
            u64 kj = gc[j];
            r += (kj < ki) || (kj == ki && j < i);
        }
        if (r < (uint32_t)Kb)
            outb[r] = make_float2(funmap((uint32_t)(ki >> 32)), funmap((uint32_t)ki));
    }
}

extern "C" void kernel_launch(void* const* d_in, const int* in_sizes, int n_in,
                              void* d_out, int out_size, void* d_ws, size_t ws_size,
                              hipStream_t stream) {
    const float* corners = (const float*)d_in[0];
    const int* lengths   = (const int*)d_in[1];
    float* out = (float*)d_out;
    const int B = in_sizes[1];
    const int M = in_sizes[0] / (B * 2);
    const int NCH = (M + CH - 1) / CH;   // 8 for M=32768

    char* w = (char*)d_ws;
    u64* keys = (u64*)w;                      w += (size_t)B * NCH * SLOTC * sizeof(u64);
    uint32_t* counts = (uint32_t*)w;          w += (size_t)B * NCH * sizeof(uint32_t);
    uint32_t* done = (uint32_t*)w;            w += (size_t)B * sizeof(uint32_t);
    uint32_t* fbh = (uint32_t*)w;             w += (size_t)B * FNB * sizeof(uint32_t);
    u64* fbc = (u64*)w;

    hipMemsetAsync(done, 0, (size_t)B * sizeof(uint32_t), stream);
    topk_kernel<<<B * NCH, FTH, 0, stream>>>(corners, lengths, out, keys, counts,
                                             done, fbh, fbc, M, NCH);
}

// Round 20
// 23.848 us; speedup vs baseline: 17.9601x; 17.9601x over previous
//
#include <hip/hip_runtime.h>
#include <stdint.h>
#include <math.h>

typedef unsigned long long u64;

#define NT     1024
#define KOUT   512
#define DIRECT 1024     // L <= DIRECT: load rows directly, no filter
#define NBK    1024     // sort buckets
#define MAXB   48       // per-bucket guard
#define FNB    4096     // fallback histogram bins
#define FCAP   2048     // fallback candidate buffer

// Monotone float->uint32 map (order-preserving), exactly invertible.
__device__ __forceinline__ uint32_t fmap(float f) {
    uint32_t u = __float_as_uint(f);
    return (u & 0x80000000u) ? ~u : (u | 0x80000000u);
}
__device__ __forceinline__ float funmap(uint32_t m) {
    uint32_t u = (m & 0x80000000u) ? (m & 0x7fffffffu) : ~m;
    return __uint_as_float(u);
}
__device__ __forceinline__ u64 pack(float x, float y) {
    return ((u64)fmap(x) << 32) | (u64)fmap(y);
}

// Acklam inverse normal CDF (float); ~1e-3 accuracy, exactness guarded downstream.
__device__ __forceinline__ float norm_icdf(float p) {
    const float a1=-3.969683028665376e+01f,a2= 2.209460984245205e+02f,a3=-2.759285104469687e+02f,
                a4= 1.383577518672690e+02f,a5=-3.066479806614716e+01f,a6= 2.506628277459239e+00f;
    const float b1=-5.447609879822406e+01f,b2= 1.615858368580409e+02f,b3=-1.556989798598866e+02f,
                b4= 6.680131188771972e+01f,b5=-1.328068155288572e+01f;
    const float c1=-7.784894002430293e-03f,c2=-3.223964580411365e-01f,c3=-2.400758277161838e+00f,
                c4=-2.549732539343734e+00f,c5= 4.374664141464968e+00f,c6= 2.938163982698783e+00f;
    const float d1= 7.784695709041462e-03f,d2= 3.224671290700398e-01f,d3= 2.445134137142996e+00f,
                d4= 3.754408661907416e+00f;
    if (p < 0.02425f) {
        float q = sqrtf(-2.0f * logf(p));
        return (((((c1*q+c2)*q+c3)*q+c4)*q+c5)*q+c6) / ((((d1*q+d2)*q+d3)*q+d4)*q+1.0f);
    } else if (p <= 0.97575f) {
        float q = p - 0.5f, r = q*q;
        return (((((a1*r+a2)*r+a3)*r+a4)*r+a5)*r+a6)*q / (((((b1*r+b2)*r+b3)*r+b4)*r+b5)*r+1.0f);
    } else {
        float q = sqrtf(-2.0f * logf(1.0f - p));
        return -(((((c1*q+c2)*q+c3)*q+c4)*q+c5)*q+c6) / ((((d1*q+d2)*q+d3)*q+d4)*q+1.0f);
    }
}

__global__ __launch_bounds__(NT) void topk_kernel(
    const float* __restrict__ corners, const int* __restrict__ lengths,
    float* __restrict__ out, int M, int B)
{
    const int tid = threadIdx.x;

    __shared__ u64 sbuf[NT];         // candidate buffer / scatter target
    __shared__ uint32_t bh[NBK];     // bucket counts
    __shared__ uint32_t sc[NBK];     // bucket starts (exclusive scan)
    __shared__ uint32_t wsum[16];
    __shared__ uint32_t hist[FNB];   // fallback only
    __shared__ u64 fcand[FCAP];      // fallback only
    __shared__ uint32_t skey[NT];    // length-rank scatter target
    __shared__ uint16_t sinv[NT];
    __shared__ uint32_t shcnt, shT, ovf;

    // ---- length-rank prepass via counting sort (~0.3 us, exact) ----
    // sinv[r] = batch id with r-th smallest length.
    const bool pair_mode = (B <= NT) && ((B & 1) == 0);
    if (pair_mode) {
        uint32_t mykey = 0, bkt0 = 0;
        const bool pv = (tid < B);
        if (pv) {
            int l = lengths[tid];
            if (l < 0) l = 0;
            if (l > M) l = M;
            mykey = ((uint32_t)l << 10) | (uint32_t)tid;   // unique keys
            float fb0 = (float)l * ((float)NBK / ((float)M + 1.0f));
            uint32_t bb = (uint32_t)fb0;
            bkt0 = (bb > (NBK - 1u)) ? (NBK - 1u) : bb;
        }
        bh[tid] = 0u;
        __syncthreads();
        if (pv) atomicAdd(&bh[bkt0], 1u);
        __syncthreads();
        {
            const uint32_t c = bh[tid];
            const int lane = tid & 63, wid = tid >> 6;
            uint32_t v = c;
            for (int off = 1; off < 64; off <<= 1) {
                uint32_t t2 = __shfl_up(v, (unsigned)off, 64);
                if (lane >= off) v += t2;
            }
            if (lane == 63) wsum[wid] = v;
            __syncthreads();
            if (tid < 16) {
                uint32_t xv = wsum[tid];
                for (int off = 1; off < 16; off <<= 1) {
                    uint32_t t2 = __shfl_up(xv, (unsigned)off, 16);
                    if (tid >= off) xv += t2;
                }
                wsum[tid] = xv;
            }
            __syncthreads();
            const uint32_t woff = (wid > 0) ? wsum[wid - 1] : 0u;
            sc[tid] = v + woff - c;
        }
        __syncthreads();
        bh[tid] = 0u;
        __syncthreads();
        uint32_t pos = 0;
        if (pv) {
            uint32_t off = atomicAdd(&bh[bkt0], 1u);
            pos = sc[bkt0] + off;
            skey[pos] = mykey;
        }
        __syncthreads();
        if (pv) {
            const uint32_t s0 = sc[bkt0];
            const uint32_t cnt = bh[bkt0];
            uint32_t r = 0;
            for (uint32_t m = 0; m < cnt; ++m) {
                uint32_t kj = skey[s0 + m];
                r += (kj < mykey) || (kj == mykey && (s0 + m) < pos);
            }
            sinv[s0 + r] = (uint16_t)tid;
        }
        __syncthreads();
    }

    // ---- batch assignment: blocks 2c/2c+1 (hypothesized same-CU) get
    //      complementary ranks c / B-1-c -> per-CU work ~ mean ----
    int b;
    if (pair_mode) {
        const int pc = (int)(blockIdx.x >> 1);
        const int myrank = (blockIdx.x & 1) ? (B - 1 - pc) : pc;
        b = (int)sinv[myrank];
    } else {
        b = (int)blockIdx.x;
    }
    __syncthreads();

    int L = lengths[b];
    if (L < 0) L = 0;
    if (L > M) L = M;
    const int Kb = (L < KOUT) ? L : KOUT;
    float2* outb = (float2*)(out + (size_t)b * (2 * KOUT));

    if (L == 0) {
        if (tid < KOUT) outb[tid] = make_float2(0.0f, 0.0f);
        return;
    }

    const float2* cp = (const float2*)corners + (size_t)b * M;
    bool fb = false;
    uint32_t n = 0;

    if (L <= DIRECT) {
        // ---- direct path: every valid row is a candidate ----
        n = (uint32_t)L;
        sbuf[tid] = (tid < L) ? pack(cp[tid].x, cp[tid].y) : ~0ull;
    } else {
        // ---- filtered path: keep x <= tau(L), expected n ~ 768 +- 28 ----
        if (tid == 0) shcnt = 0u;
        __syncthreads();
        const float tau = norm_icdf(768.0f / (float)L) + 0.01f;
        const int lane = tid & 63;
        const float4* cp4 = (const float4*)cp;
        const int nv = L >> 1;

        for (int i = tid; i < nv; i += NT) {
            float4 v = cp4[i];
            bool c0k = (v.x <= tau), c1k = (v.z <= tau);
            u64 m0 = __ballot(c0k), m1 = __ballot(c1k);
            if (m0 | m1) {
                int c0 = __popcll(m0);
                uint32_t base = 0;
                if (lane == 0) base = atomicAdd(&shcnt, (uint32_t)(c0 + __popcll(m1)));
                base = __shfl(base, 0, 64);
                u64 lt = ((u64)1 << lane) - 1ull;
                if (c0k) {
                    uint32_t s = base + (uint32_t)__popcll(m0 & lt);
                    if (s < NT) sbuf[s] = pack(v.x, v.y);
                }
                if (c1k) {
                    uint32_t s = base + (uint32_t)(c0 + __popcll(m1 & lt));
                    if (s < NT) sbuf[s] = pack(v.z, v.w);
                }
            }
        }
        if ((L & 1) && tid == 0) {
            float2 c = cp[L - 1];
            if (c.x <= tau) {
                uint32_t s = atomicAdd(&shcnt, 1u);
                if (s < NT) sbuf[s] = pack(c.x, c.y);
            }
        }
        __syncthreads();
        n = shcnt;
        if (n < (uint32_t)Kb || n > NT) fb = true;     // block-uniform
        else if (tid >= (int)n) sbuf[tid] = ~0ull;     // sentinel-pad
    }

    if (!fb) {
        __syncthreads();   // sbuf fully populated

        // ---- bucketed counting-sort rank ----
        u64 key = sbuf[tid];
        const bool valid = (tid < (int)n);
        uint32_t bkt = 0;
        if (valid) {
            float x = funmap((uint32_t)(key >> 32));
            float p = 0.5f * (1.0f + erff(x * 0.70710678f));   // Phi(x)
            float s = (L > DIRECT) ? ((float)L * ((float)NBK / 768.0f))
                                   : (float)NBK;
            float fp = p * s;
            uint32_t bb = (uint32_t)fp;
            bkt = (bb > (NBK - 1u)) ? (NBK - 1u) : bb;
        }

        bh[tid] = 0u;
        if (tid == 0) ovf = 0u;
        __syncthreads();
        if (valid) atomicAdd(&bh[bkt], 1u);
        __syncthreads();

        // exclusive scan of bh -> sc (wave shuffle scan + wave-sum scan)
        {
            const uint32_t c = bh[tid];
            const int lane = tid & 63, wid = tid >> 6;
            uint32_t v = c;
            for (int off = 1; off < 64; off <<= 1) {
                uint32_t t2 = __shfl_up(v, (unsigned)off, 64);
                if (lane >= off) v += t2;
            }
            if (lane == 63) wsum[wid] = v;
            __syncthreads();
            if (tid < 16) {
                uint32_t xv = wsum[tid];
                for (int off = 1; off < 16; off <<= 1) {
                    uint32_t t2 = __shfl_up(xv, (unsigned)off, 16);
                    if (tid >= off) xv += t2;
                }
                wsum[tid] = xv;
            }
            __syncthreads();
            const uint32_t woff = (wid > 0) ? wsum[wid - 1] : 0u;
            sc[tid] = v + woff - c;
        }
        __syncthreads();
        bh[tid] = 0u;
        __syncthreads();

        // scatter by bucket (keys already in registers; sbuf reusable)
        uint32_t pos = 0;
        if (valid) {
            uint32_t off = atomicAdd(&bh[bkt], 1u);
            pos = sc[bkt] + off;
            sbuf[pos] = key;
        }
        __syncthreads();
        if (valid && bh[bkt] > MAXB) ovf = 1u;   // benign race, all write 1
        __syncthreads();

        if (ovf == 0u) {   // block-uniform
            // exact global rank = bucket start + rank within bucket
            uint32_t rank = 0;
            if (valid) {
                const uint32_t s0 = sc[bkt];
                const uint32_t cnt = bh[bkt];
                uint32_t r = 0;
                for (uint32_t m = 0; m < cnt; ++m) {
                    u64 kj = sbuf[s0 + m];
                    r += (kj < key) || (kj == key && (s0 + m) < pos);
                }
                rank = s0 + r;
            }
            if (tid >= Kb && tid < KOUT)
                outb[tid] = make_float2(0.0f, 0.0f);
            if (valid && rank < (uint32_t)Kb) {
                float2 o;
                o.x = funmap((uint32_t)(key >> 32));
                o.y = funmap((uint32_t)key);
                outb[rank] = o;
            }
            return;
        }
        // bucket overflow (statistically unreachable) -> exact fallback below
    }

    // ---- exact fallback (statistically unreachable; guards exact) ----
    __syncthreads();
    if (tid == 0) { shcnt = 0u; shT = FNB - 1; }
    for (int i = tid; i < FNB; i += NT) hist[i] = 0u;
    __syncthreads();
    for (int i = tid; i < L; i += NT)
        atomicAdd(&hist[fmap(cp[i].x) >> 20], 1u);
    __syncthreads();
    if (tid == 0) {
        uint32_t run = 0;
        for (int g = 0; g < FNB; ++g) {
            run += hist[g];
            if (run >= (uint32_t)Kb) { shT = (uint32_t)g; break; }
        }
    }
    __syncthreads();
    const uint32_t T = shT;
    for (int i = tid; i < L; i += NT) {
        float2 c = cp[i];
        uint32_t kx = fmap(c.x);
        if ((kx >> 20) <= T) {
            uint32_t p = atomicAdd(&shcnt, 1u);
            if (p < FCAP) fcand[p] = ((u64)kx << 32) | fmap(c.y);
        }
    }
    __syncthreads();
    const int nn = (int)((shcnt < FCAP) ? shcnt : FCAP);
    for (int jj = Kb + tid; jj < KOUT; jj += NT)
        outb[jj] = make_float2(0.0f, 0.0f);
    for (int i = tid; i < nn; i += NT) {
        u64 ki = fcand[i];
        uint32_t r = 0;
        for (int jj = 0; jj < nn; ++jj) {
            u64 kj = fcand[jj];
            r += (kj < ki) || (kj == ki && jj < i);
        }
        if (r < (uint32_t)Kb)
            outb[r] = make_float2(funmap((uint32_t)(ki >> 32)), funmap((uint32_t)ki));
    }
}

extern "C" void kernel_launch(void* const* d_in, const int* in_sizes, int n_in,
                              void* d_out, int out_size, void* d_ws, size_t ws_size,
                              hipStream_t stream) {
    const float* corners = (const float*)d_in[0];
    const int* lengths   = (const int*)d_in[1];
    float* out = (float*)d_out;
    const int B = in_sizes[1];
    const int M = in_sizes[0] / (B * 2);
    topk_kernel<<<B, NT, 0, stream>>>(corners, lengths, out, M, B);
}